// Round 1
// baseline (3586.340 us; speedup 1.0000x reference)
//
#include <hip/hip_runtime.h>
#include <math.h>

#define NB 256
#define IMG 256
#define GSZ 64
#define HID 512
#define NSTEP 16

#define APITCH 260                      // padded LDS row pitch (floats)
#define GLDS_FLOATS (2*64*APITCH + 128) // A(64x260) + Bf(64x260) + invA(64) + invW(64)
#define GLDS_BYTES (GLDS_FLOATS*4)

// ---------------- params: gp = tanh(Hx @ W_g^T + b_g) -> filter params ----------------
__global__ __launch_bounds__(64) void k_params(const float* __restrict__ Hx,
                                               const float* __restrict__ W_g,
                                               const float* __restrict__ b_g,
                                               float* __restrict__ params) {
    const int b = blockIdx.x;
    const int l = threadIdx.x;
    float s0 = 0.f, s1 = 0.f, s2 = 0.f;
    const float* h = Hx + (size_t)b * HID;
    for (int k = l; k < HID; k += 64) {
        float hv = h[k];
        s0 += hv * W_g[k];
        s1 += hv * W_g[HID + k];
        s2 += hv * W_g[2 * HID + k];
    }
    for (int off = 32; off; off >>= 1) {
        s0 += __shfl_xor(s0, off, 64);
        s1 += __shfl_xor(s1, off, 64);
        s2 += __shfl_xor(s2, off, 64);
    }
    if (l == 0) {
        float g0 = tanhf(s0 + b_g[0]);   // h center caps
        float g1 = tanhf(s1 + b_g[1]);   // w center caps
        float g2 = tanhf(s2 + b_g[2]);   // delta caps
        float ad = fabsf(g2);
        params[b * 4 + 0] = 127.5f * (g0 + 1.0f);        // center_h = (I-1)(c+1)/2
        params[b * 4 + 1] = 127.5f * (g1 + 1.0f);        // center_w
        params[b * 4 + 2] = 4.0f * (1.0f - ad);          // delta = I/G*(1-|d|)
        params[b * 4 + 3] = expf(1.0f - 2.0f * ad);      // gamma
    }
}

// ---------------- glimpse: x[b] = norm(Fh) @ img @ norm(Fw)^T ----------------
__global__ __launch_bounds__(256) void k_glimpse(const float* __restrict__ params,
                                                 const float* __restrict__ imgs,
                                                 int sel, float* __restrict__ x) {
    extern __shared__ float sm[];
    float* A    = sm;                    // 64 x APITCH : Fh, later g
    float* Bf   = sm + 64 * APITCH;      // 64 x APITCH : Fw
    float* invA = sm + 2 * 64 * APITCH;  // 64
    float* invW = invA + 64;             // 64

    const int b = blockIdx.x;
    const int t = threadIdx.x;
    const float ch = params[b * 4 + 0];
    const float cw = params[b * 4 + 1];
    const float dl = params[b * 4 + 2];
    const float gm = params[b * 4 + 3];
    const float ig = 1.0f / gm;
    const float coef = 1.0f / (3.14159265358979323846f * gm);

    // ---- fill Fh (unnormalized): A[gh][pix], thread t = pix ----
    {
        const float base = (float)t - ch;
        for (int gh = 0; gh < 64; ++gh) {
            float u = (base - dl * ((float)gh - 31.5f)) * ig;
            A[gh * APITCH + t] = coef / (1.0f + u * u);
        }
    }
    __syncthreads();
    // ---- Fh row sums -> invA ----
    {
        const int wid = t >> 6, lane = t & 63;
        for (int r = wid; r < 64; r += 4) {
            const float* row = A + r * APITCH;
            float s = row[lane] + row[lane + 64] + row[lane + 128] + row[lane + 192];
            for (int off = 32; off; off >>= 1) s += __shfl_xor(s, off, 64);
            if (lane == 0) invA[r] = 1.0f / (s + 1e-4f);
        }
    }
    __syncthreads();

    // ---- phase 1: g[gh][w] = sum_h Fh[gh][h] * img[h][w]  (acc in regs) ----
    const int ghl = t & 7;             // thread's gh set: ghl + 8*i
    const int wb  = (t >> 3) * 8;      // thread's w set: wb + j (j=0..7)
    float acc[8][8];
    #pragma unroll
    for (int i = 0; i < 8; ++i)
        #pragma unroll
        for (int j = 0; j < 8; ++j) acc[i][j] = 0.f;

    const float* imgp = imgs + ((size_t)(b * 2 + sel)) * (IMG * IMG);
    for (int h0 = 0; h0 < IMG; h0 += 4) {
        float4 fh[8];
        #pragma unroll
        for (int i = 0; i < 8; ++i)
            fh[i] = *(const float4*)&A[(ghl + 8 * i) * APITCH + h0];
        #pragma unroll
        for (int r = 0; r < 4; ++r) {
            float4 i0 = *(const float4*)&imgp[(size_t)(h0 + r) * IMG + wb];
            float4 i1 = *(const float4*)&imgp[(size_t)(h0 + r) * IMG + wb + 4];
            float iv[8] = {i0.x, i0.y, i0.z, i0.w, i1.x, i1.y, i1.z, i1.w};
            #pragma unroll
            for (int i = 0; i < 8; ++i) {
                float fv = (r == 0) ? fh[i].x : (r == 1) ? fh[i].y : (r == 2) ? fh[i].z : fh[i].w;
                #pragma unroll
                for (int j = 0; j < 8; ++j) acc[i][j] += fv * iv[j];
            }
        }
    }
    // fold Fh normalization into g
    {
        float sA[8];
        #pragma unroll
        for (int i = 0; i < 8; ++i) sA[i] = invA[ghl + 8 * i];
        #pragma unroll
        for (int i = 0; i < 8; ++i)
            #pragma unroll
            for (int j = 0; j < 8; ++j) acc[i][j] *= sA[i];
    }
    __syncthreads();   // all Fh reads done -> safe to overwrite A with g
    #pragma unroll
    for (int i = 0; i < 8; ++i) {
        float4 v0 = make_float4(acc[i][0], acc[i][1], acc[i][2], acc[i][3]);
        float4 v1 = make_float4(acc[i][4], acc[i][5], acc[i][6], acc[i][7]);
        *(float4*)&A[(ghl + 8 * i) * APITCH + wb] = v0;
        *(float4*)&A[(ghl + 8 * i) * APITCH + wb + 4] = v1;
    }
    // ---- fill Fw (unnormalized) ----
    {
        const float basew = (float)t - cw;
        for (int gw = 0; gw < 64; ++gw) {
            float u = (basew - dl * ((float)gw - 31.5f)) * ig;
            Bf[gw * APITCH + t] = coef / (1.0f + u * u);
        }
    }
    __syncthreads();
    // ---- Fw row sums -> invW ----
    {
        const int wid = t >> 6, lane = t & 63;
        for (int r = wid; r < 64; r += 4) {
            const float* row = Bf + r * APITCH;
            float s = row[lane] + row[lane + 64] + row[lane + 128] + row[lane + 192];
            for (int off = 32; off; off >>= 1) s += __shfl_xor(s, off, 64);
            if (lane == 0) invW[r] = 1.0f / (s + 1e-4f);
        }
    }
    __syncthreads();

    // ---- phase 2: x[gh][gw] = (sum_w g[gh][w]*Fw[gw][w]) * invW[gw] ----
    const int gh2 = (t >> 4) * 4;   // gh rows: gh2 + i (i=0..3)
    const int gw2 = t & 15;         // gw cols: gw2 + 16*j (j=0..3)
    float a2[4][4];
    #pragma unroll
    for (int i = 0; i < 4; ++i)
        #pragma unroll
        for (int j = 0; j < 4; ++j) a2[i][j] = 0.f;

    for (int w0 = 0; w0 < IMG; w0 += 4) {
        float4 ga[4], fw[4];
        #pragma unroll
        for (int i = 0; i < 4; ++i) ga[i] = *(const float4*)&A[(gh2 + i) * APITCH + w0];
        #pragma unroll
        for (int j = 0; j < 4; ++j) fw[j] = *(const float4*)&Bf[(gw2 + 16 * j) * APITCH + w0];
        #pragma unroll
        for (int i = 0; i < 4; ++i)
            #pragma unroll
            for (int j = 0; j < 4; ++j)
                a2[i][j] += ga[i].x * fw[j].x + ga[i].y * fw[j].y + ga[i].z * fw[j].z + ga[i].w * fw[j].w;
    }
    float* xo = x + (size_t)b * (GSZ * GSZ);
    #pragma unroll
    for (int j = 0; j < 4; ++j) {
        float s = invW[gw2 + 16 * j];
        #pragma unroll
        for (int i = 0; i < 4; ++i)
            xo[(gh2 + i) * GSZ + gw2 + 16 * j] = a2[i][j] * s;
    }
}

// ---------------- gates GEMM: gates = x@W_ih^T + Hx@W_hh^T + b_ih + b_hh ----------------
__global__ __launch_bounds__(256) void k_gates(const float* __restrict__ x,
                                               const float* __restrict__ Hx,
                                               const float* __restrict__ W_ih,
                                               const float* __restrict__ W_hh,
                                               const float* __restrict__ b_ih,
                                               const float* __restrict__ b_hh,
                                               float* __restrict__ gates) {
    __shared__ float As[32][36];   // As[k][m]
    __shared__ float Bs[32][68];   // Bs[k][j]
    const int t  = threadIdx.x;
    const int bm = blockIdx.x >> 5;    // 0..7
    const int bn = blockIdx.x & 31;    // 0..31
    const int m0 = bm * 32, n0 = bn * 64;
    const int lr = t >> 3;             // 0..31
    const int lc = (t & 7) * 4;        // 0..28
    const int tm = t >> 4;             // 0..15
    const int tn = t & 15;             // 0..15

    float acc[2][4];
    #pragma unroll
    for (int i = 0; i < 2; ++i)
        #pragma unroll
        for (int j = 0; j < 4; ++j) acc[i][j] = 0.f;

    #pragma unroll 1
    for (int seg = 0; seg < 2; ++seg) {
        const float* Aseg = seg ? Hx : x;
        const float* Wseg = seg ? W_hh : W_ih;
        const int K = seg ? HID : (GSZ * GSZ);
        for (int k0 = 0; k0 < K; k0 += 32) {
            float4 av  = *(const float4*)&Aseg[(size_t)(m0 + lr) * K + k0 + lc];
            float4 bv0 = *(const float4*)&Wseg[(size_t)(n0 + lr) * K + k0 + lc];
            float4 bv1 = *(const float4*)&Wseg[(size_t)(n0 + lr + 32) * K + k0 + lc];
            __syncthreads();
            As[lc + 0][lr] = av.x; As[lc + 1][lr] = av.y;
            As[lc + 2][lr] = av.z; As[lc + 3][lr] = av.w;
            Bs[lc + 0][lr] = bv0.x; Bs[lc + 1][lr] = bv0.y;
            Bs[lc + 2][lr] = bv0.z; Bs[lc + 3][lr] = bv0.w;
            Bs[lc + 0][lr + 32] = bv1.x; Bs[lc + 1][lr + 32] = bv1.y;
            Bs[lc + 2][lr + 32] = bv1.z; Bs[lc + 3][lr + 32] = bv1.w;
            __syncthreads();
            #pragma unroll
            for (int k = 0; k < 32; ++k) {
                float2 a  = *(const float2*)&As[k][2 * tm];
                float4 bv = *(const float4*)&Bs[k][4 * tn];
                acc[0][0] += a.x * bv.x; acc[0][1] += a.x * bv.y;
                acc[0][2] += a.x * bv.z; acc[0][3] += a.x * bv.w;
                acc[1][0] += a.y * bv.x; acc[1][1] += a.y * bv.y;
                acc[1][2] += a.y * bv.z; acc[1][3] += a.y * bv.w;
            }
        }
    }
    #pragma unroll
    for (int ii = 0; ii < 2; ++ii) {
        const int m = m0 + 2 * tm + ii;
        #pragma unroll
        for (int jj = 0; jj < 4; ++jj) {
            const int j = n0 + 4 * tn + jj;
            gates[(size_t)m * (4 * HID) + j] = acc[ii][jj] + b_ih[j] + b_hh[j];
        }
    }
}

// ---------------- pointwise LSTM update ----------------
__global__ __launch_bounds__(256) void k_lstm(const float* __restrict__ gates,
                                              float* __restrict__ Cx,
                                              float* __restrict__ Hx,
                                              float* __restrict__ out) {
    const int id = blockIdx.x * 256 + threadIdx.x;   // < NB*HID
    const int b = id >> 9, u = id & (HID - 1);
    const float* gr = gates + (size_t)b * (4 * HID);
    float gi = gr[u];
    float gf = gr[HID + u];
    float gg = gr[2 * HID + u];
    float go = gr[3 * HID + u];
    float si = 1.0f / (1.0f + expf(-gi));
    float sf = 1.0f / (1.0f + expf(-gf));
    float so = 1.0f / (1.0f + expf(-go));
    float c = sf * Cx[id] + si * tanhf(gg);
    float h = so * tanhf(c);
    Cx[id] = c;
    Hx[id] = h;
    out[id] = h;
}

extern "C" void kernel_launch(void* const* d_in, const int* in_sizes, int n_in,
                              void* d_out, int out_size, void* d_ws, size_t ws_size,
                              hipStream_t stream) {
    const float* imgs = (const float*)d_in[0];
    const float* W_ih = (const float*)d_in[1];
    const float* W_hh = (const float*)d_in[2];
    const float* b_ih = (const float*)d_in[3];
    const float* b_hh = (const float*)d_in[4];
    const float* W_g  = (const float*)d_in[5];
    const float* b_g  = (const float*)d_in[6];
    float* out = (float*)d_out;

    float* ws     = (float*)d_ws;
    float* params = ws;                        // 1024 floats
    float* Hx     = ws + 1024;                 // 131072
    float* Cx     = Hx + NB * HID;             // 131072
    float* x      = Cx + NB * HID;             // 1048576
    float* gates  = x + NB * GSZ * GSZ;        // 524288

    (void)hipFuncSetAttribute((const void*)k_glimpse,
                              hipFuncAttributeMaxDynamicSharedMemorySize, GLDS_BYTES);

    // Hx = Cx = 0 (ws is poisoned, not re-poisoned between replays)
    hipMemsetAsync(Hx, 0, (size_t)2 * NB * HID * sizeof(float), stream);

    for (int step = 0; step < NSTEP; ++step) {
        k_params<<<NB, 64, 0, stream>>>(Hx, W_g, b_g, params);
        k_glimpse<<<NB, 256, GLDS_BYTES, stream>>>(params, imgs, step & 1, x);
        k_gates<<<256, 256, 0, stream>>>(x, Hx, W_ih, W_hh, b_ih, b_hh, gates);
        k_lstm<<<NB * HID / 256, 256, 0, stream>>>(gates, Cx, Hx, out);
    }
}

// Round 2
// 1534.845 us; speedup vs baseline: 2.3366x; 2.3366x over previous
//
#include <hip/hip_runtime.h>
#include <math.h>

#define NB 256
#define IMG 256
#define GSZ 64
#define HID 512
#define NSTEP 16
#define KTOT 4608            // 4096 (x) + 512 (Hx)
#define SPLITK 8
#define KCHUNK 576           // KTOT / SPLITK
#define KSTEPS 18            // KCHUNK / 32

#define APITCH 260                      // glimpse LDS pitch (floats)
#define GLDS_FLOATS (2*64*APITCH + 128)
#define GLDS_BYTES (GLDS_FLOATS*4)

typedef unsigned short u16;
typedef __attribute__((ext_vector_type(8))) short s16x8;   // 8 bf16
typedef __attribute__((ext_vector_type(4))) float f32x4;

__device__ inline u16 f2bf(float f) {           // round-to-nearest-even bf16
    unsigned u = __float_as_uint(f);
    unsigned r = u + 0x7fffu + ((u >> 16) & 1u);
    return (u16)(r >> 16);
}
__device__ inline float bf2f(u16 h) { return __uint_as_float((unsigned)h << 16); }

// ---------------- weight split (once per launch): Wc = [W_ih | W_hh] -> hi/lo bf16 ----------------
__global__ __launch_bounds__(256) void k_wsplit(const float* __restrict__ W_ih,
                                                const float* __restrict__ W_hh,
                                                u16* __restrict__ wc_hi,
                                                u16* __restrict__ wc_lo) {
    // 2048 x 4608 elems, processed as float4 chunks
    const int nchunk = 2048 * KTOT / 4;          // 2359296
    const int stride = gridDim.x * blockDim.x;   // 589824
    for (int c = blockIdx.x * blockDim.x + threadIdx.x; c < nchunk; c += stride) {
        const int j = c / (KTOT / 4);
        const int k = (c - j * (KTOT / 4)) * 4;
        float4 v;
        if (k < 4096) v = *(const float4*)&W_ih[(size_t)j * 4096 + k];
        else          v = *(const float4*)&W_hh[(size_t)j * 512 + (k - 4096)];
        float f[4] = {v.x, v.y, v.z, v.w};
        u16 hi[4], lo[4];
        #pragma unroll
        for (int i = 0; i < 4; ++i) {
            hi[i] = f2bf(f[i]);
            lo[i] = f2bf(f[i] - bf2f(hi[i]));
        }
        const size_t o = (size_t)j * KTOT + k;
        *(ushort4*)&wc_hi[o] = make_ushort4(hi[0], hi[1], hi[2], hi[3]);
        *(ushort4*)&wc_lo[o] = make_ushort4(lo[0], lo[1], lo[2], lo[3]);
    }
}

// ---------------- params: gp = tanh(Hx @ W_g^T + b_g) -> filter params ----------------
__global__ __launch_bounds__(64) void k_params(const float* __restrict__ Hx,
                                               const float* __restrict__ W_g,
                                               const float* __restrict__ b_g,
                                               float* __restrict__ params) {
    const int b = blockIdx.x;
    const int l = threadIdx.x;
    float s0 = 0.f, s1 = 0.f, s2 = 0.f;
    const float* h = Hx + (size_t)b * HID;
    for (int k = l; k < HID; k += 64) {
        float hv = h[k];
        s0 += hv * W_g[k];
        s1 += hv * W_g[HID + k];
        s2 += hv * W_g[2 * HID + k];
    }
    for (int off = 32; off; off >>= 1) {
        s0 += __shfl_xor(s0, off, 64);
        s1 += __shfl_xor(s1, off, 64);
        s2 += __shfl_xor(s2, off, 64);
    }
    if (l == 0) {
        float g0 = tanhf(s0 + b_g[0]);
        float g1 = tanhf(s1 + b_g[1]);
        float g2 = tanhf(s2 + b_g[2]);
        float ad = fabsf(g2);
        params[b * 4 + 0] = 127.5f * (g0 + 1.0f);
        params[b * 4 + 1] = 127.5f * (g1 + 1.0f);
        params[b * 4 + 2] = 4.0f * (1.0f - ad);
        params[b * 4 + 3] = expf(1.0f - 2.0f * ad);
    }
}

// ---------------- glimpse: x[b] = norm(Fh) @ img @ norm(Fw)^T -> bf16 hi/lo ----------------
__global__ __launch_bounds__(256) void k_glimpse(const float* __restrict__ params,
                                                 const float* __restrict__ imgs,
                                                 int sel,
                                                 u16* __restrict__ xh,
                                                 u16* __restrict__ xl) {
    extern __shared__ float sm[];
    float* A    = sm;
    float* Bf   = sm + 64 * APITCH;
    float* invA = sm + 2 * 64 * APITCH;
    float* invW = invA + 64;

    const int b = blockIdx.x;
    const int t = threadIdx.x;
    const float ch = params[b * 4 + 0];
    const float cw = params[b * 4 + 1];
    const float dl = params[b * 4 + 2];
    const float gm = params[b * 4 + 3];
    const float ig = 1.0f / gm;
    const float coef = 1.0f / (3.14159265358979323846f * gm);

    {
        const float base = (float)t - ch;
        for (int gh = 0; gh < 64; ++gh) {
            float u = (base - dl * ((float)gh - 31.5f)) * ig;
            A[gh * APITCH + t] = coef / (1.0f + u * u);
        }
    }
    __syncthreads();
    {
        const int wid = t >> 6, lane = t & 63;
        for (int r = wid; r < 64; r += 4) {
            const float* row = A + r * APITCH;
            float s = row[lane] + row[lane + 64] + row[lane + 128] + row[lane + 192];
            for (int off = 32; off; off >>= 1) s += __shfl_xor(s, off, 64);
            if (lane == 0) invA[r] = 1.0f / (s + 1e-4f);
        }
    }
    __syncthreads();

    const int ghl = t & 7;
    const int wb  = (t >> 3) * 8;
    float acc[8][8];
    #pragma unroll
    for (int i = 0; i < 8; ++i)
        #pragma unroll
        for (int j = 0; j < 8; ++j) acc[i][j] = 0.f;

    const float* imgp = imgs + ((size_t)(b * 2 + sel)) * (IMG * IMG);
    for (int h0 = 0; h0 < IMG; h0 += 4) {
        float4 fh[8];
        #pragma unroll
        for (int i = 0; i < 8; ++i)
            fh[i] = *(const float4*)&A[(ghl + 8 * i) * APITCH + h0];
        #pragma unroll
        for (int r = 0; r < 4; ++r) {
            float4 i0 = *(const float4*)&imgp[(size_t)(h0 + r) * IMG + wb];
            float4 i1 = *(const float4*)&imgp[(size_t)(h0 + r) * IMG + wb + 4];
            float iv[8] = {i0.x, i0.y, i0.z, i0.w, i1.x, i1.y, i1.z, i1.w};
            #pragma unroll
            for (int i = 0; i < 8; ++i) {
                float fv = (r == 0) ? fh[i].x : (r == 1) ? fh[i].y : (r == 2) ? fh[i].z : fh[i].w;
                #pragma unroll
                for (int j = 0; j < 8; ++j) acc[i][j] += fv * iv[j];
            }
        }
    }
    {
        float sA[8];
        #pragma unroll
        for (int i = 0; i < 8; ++i) sA[i] = invA[ghl + 8 * i];
        #pragma unroll
        for (int i = 0; i < 8; ++i)
            #pragma unroll
            for (int j = 0; j < 8; ++j) acc[i][j] *= sA[i];
    }
    __syncthreads();
    #pragma unroll
    for (int i = 0; i < 8; ++i) {
        float4 v0 = make_float4(acc[i][0], acc[i][1], acc[i][2], acc[i][3]);
        float4 v1 = make_float4(acc[i][4], acc[i][5], acc[i][6], acc[i][7]);
        *(float4*)&A[(ghl + 8 * i) * APITCH + wb] = v0;
        *(float4*)&A[(ghl + 8 * i) * APITCH + wb + 4] = v1;
    }
    {
        const float basew = (float)t - cw;
        for (int gw = 0; gw < 64; ++gw) {
            float u = (basew - dl * ((float)gw - 31.5f)) * ig;
            Bf[gw * APITCH + t] = coef / (1.0f + u * u);
        }
    }
    __syncthreads();
    {
        const int wid = t >> 6, lane = t & 63;
        for (int r = wid; r < 64; r += 4) {
            const float* row = Bf + r * APITCH;
            float s = row[lane] + row[lane + 64] + row[lane + 128] + row[lane + 192];
            for (int off = 32; off; off >>= 1) s += __shfl_xor(s, off, 64);
            if (lane == 0) invW[r] = 1.0f / (s + 1e-4f);
        }
    }
    __syncthreads();

    const int gh2 = (t >> 4) * 4;
    const int gw2 = t & 15;
    float a2[4][4];
    #pragma unroll
    for (int i = 0; i < 4; ++i)
        #pragma unroll
        for (int j = 0; j < 4; ++j) a2[i][j] = 0.f;

    for (int w0 = 0; w0 < IMG; w0 += 4) {
        float4 ga[4], fw[4];
        #pragma unroll
        for (int i = 0; i < 4; ++i) ga[i] = *(const float4*)&A[(gh2 + i) * APITCH + w0];
        #pragma unroll
        for (int j = 0; j < 4; ++j) fw[j] = *(const float4*)&Bf[(gw2 + 16 * j) * APITCH + w0];
        #pragma unroll
        for (int i = 0; i < 4; ++i)
            #pragma unroll
            for (int j = 0; j < 4; ++j)
                a2[i][j] += ga[i].x * fw[j].x + ga[i].y * fw[j].y + ga[i].z * fw[j].z + ga[i].w * fw[j].w;
    }
    u16* xho = xh + (size_t)b * KTOT;
    u16* xlo = xl + (size_t)b * KTOT;
    #pragma unroll
    for (int j = 0; j < 4; ++j) {
        float s = invW[gw2 + 16 * j];
        #pragma unroll
        for (int i = 0; i < 4; ++i) {
            float v = a2[i][j] * s;
            u16 hv = f2bf(v);
            const int o = (gh2 + i) * GSZ + gw2 + 16 * j;
            xho[o] = hv;
            xlo[o] = f2bf(v - bf2f(hv));
        }
    }
}

// ---------------- gates GEMM via bf16x3 MFMA, split-K partials ----------------
// grid: bid = kc*32 + nb*2 + mb ; 256 threads = 4 waves (2x2), wave tile 64x64
__global__ __launch_bounds__(256) void k_gates(const u16* __restrict__ xcat_hi,
                                               const u16* __restrict__ xcat_lo,
                                               const u16* __restrict__ wc_hi,
                                               const u16* __restrict__ wc_lo,
                                               float* __restrict__ part) {
    __shared__ u16 smem[4][128][40];   // Ah, Al, Bh, Bl ; pitch 40 bf16 = 80 B

    const int bid = blockIdx.x;
    const int mb = bid & 1;
    const int nb = (bid >> 1) & 15;
    const int kc = bid >> 5;
    const int m0 = mb * 128, n0 = nb * 128, k0 = kc * KCHUNK;
    const int t = threadIdx.x;
    const int lane = t & 63, wid = t >> 6;
    const int wm = wid >> 1, wn = wid & 1;
    const int fr = lane & 15, kg = lane >> 4;

    // staging assignments: q = 0..7, cid = q*256+t, matrix = q>>1, idx = cid&511
    const u16* srcs[8];
    u16* dsts[8];
    #pragma unroll
    for (int q = 0; q < 8; ++q) {
        const int idx = ((q * 256 + t) & 511);
        const int row = idx >> 2;
        const int ko = (idx & 3) * 8;
        const int mat = q >> 1;
        const u16* gbase;
        if (mat == 0)      gbase = xcat_hi + (size_t)(m0 + row) * KTOT;
        else if (mat == 1) gbase = xcat_lo + (size_t)(m0 + row) * KTOT;
        else if (mat == 2) gbase = wc_hi + (size_t)(n0 + row) * KTOT;
        else               gbase = wc_lo + (size_t)(n0 + row) * KTOT;
        srcs[q] = gbase + k0 + ko;
        dsts[q] = &smem[mat][row][ko];
    }

    f32x4 acc[4][4];
    #pragma unroll
    for (int mi = 0; mi < 4; ++mi)
        #pragma unroll
        for (int ni = 0; ni < 4; ++ni) acc[mi][ni] = (f32x4)(0.f);

    s16x8 ld[8];
    #pragma unroll
    for (int q = 0; q < 8; ++q) ld[q] = *(const s16x8*)(srcs[q]);

    for (int ks = 0; ks < KSTEPS; ++ks) {
        __syncthreads();
        #pragma unroll
        for (int q = 0; q < 8; ++q) {
            *(s16x8*)(dsts[q]) = ld[q];
            srcs[q] += 32;
        }
        __syncthreads();
        if (ks + 1 < KSTEPS) {
            #pragma unroll
            for (int q = 0; q < 8; ++q) ld[q] = *(const s16x8*)(srcs[q]);
        }
        s16x8 ah[4], al[4], bh[4], bl[4];
        #pragma unroll
        for (int mi = 0; mi < 4; ++mi) {
            const int r = wm * 64 + mi * 16 + fr;
            ah[mi] = *(const s16x8*)&smem[0][r][kg * 8];
            al[mi] = *(const s16x8*)&smem[1][r][kg * 8];
        }
        #pragma unroll
        for (int ni = 0; ni < 4; ++ni) {
            const int r = wn * 64 + ni * 16 + fr;
            bh[ni] = *(const s16x8*)&smem[2][r][kg * 8];
            bl[ni] = *(const s16x8*)&smem[3][r][kg * 8];
        }
        #pragma unroll
        for (int mi = 0; mi < 4; ++mi)
            #pragma unroll
            for (int ni = 0; ni < 4; ++ni) {
                acc[mi][ni] = __builtin_amdgcn_mfma_f32_16x16x32_bf16(ah[mi], bh[ni], acc[mi][ni], 0, 0, 0);
                acc[mi][ni] = __builtin_amdgcn_mfma_f32_16x16x32_bf16(ah[mi], bl[ni], acc[mi][ni], 0, 0, 0);
                acc[mi][ni] = __builtin_amdgcn_mfma_f32_16x16x32_bf16(al[mi], bh[ni], acc[mi][ni], 0, 0, 0);
            }
    }

    float* pp = part + ((size_t)kc << 19);   // kc * 256 * 2048
    #pragma unroll
    for (int mi = 0; mi < 4; ++mi) {
        const int mbase = m0 + wm * 64 + mi * 16 + (lane >> 4) * 4;
        #pragma unroll
        for (int ni = 0; ni < 4; ++ni) {
            const int col = n0 + wn * 64 + ni * 16 + (lane & 15);
            #pragma unroll
            for (int r = 0; r < 4; ++r)
                pp[(size_t)(mbase + r) * 2048 + col] = acc[mi][ni][r];
        }
    }
}

// ---------------- pointwise LSTM update (+ split-K reduce, biases) ----------------
__global__ __launch_bounds__(256) void k_lstm(const float* __restrict__ part,
                                              const float* __restrict__ b_ih,
                                              const float* __restrict__ b_hh,
                                              float* __restrict__ Cx,
                                              float* __restrict__ Hx,
                                              float* __restrict__ out,
                                              u16* __restrict__ xcat_hi,
                                              u16* __restrict__ xcat_lo) {
    const int id = blockIdx.x * 256 + threadIdx.x;   // < NB*HID
    const int b = id >> 9, u = id & (HID - 1);
    float gi = b_ih[u] + b_hh[u];
    float gf = b_ih[HID + u] + b_hh[HID + u];
    float gg = b_ih[2 * HID + u] + b_hh[2 * HID + u];
    float go = b_ih[3 * HID + u] + b_hh[3 * HID + u];
    const float* pb = part + (size_t)b * 2048;
    #pragma unroll
    for (int kc = 0; kc < SPLITK; ++kc) {
        const float* p = pb + (size_t)kc * (256 * 2048);
        gi += p[u];
        gf += p[HID + u];
        gg += p[2 * HID + u];
        go += p[3 * HID + u];
    }
    float si = 1.0f / (1.0f + expf(-gi));
    float sf = 1.0f / (1.0f + expf(-gf));
    float so = 1.0f / (1.0f + expf(-go));
    float c = sf * Cx[id] + si * tanhf(gg);
    float h = so * tanhf(c);
    Cx[id] = c;
    Hx[id] = h;
    out[id] = h;
    u16 hh = f2bf(h);
    xcat_hi[(size_t)b * KTOT + 4096 + u] = hh;
    xcat_lo[(size_t)b * KTOT + 4096 + u] = f2bf(h - bf2f(hh));
}

extern "C" void kernel_launch(void* const* d_in, const int* in_sizes, int n_in,
                              void* d_out, int out_size, void* d_ws, size_t ws_size,
                              hipStream_t stream) {
    const float* imgs = (const float*)d_in[0];
    const float* W_ih = (const float*)d_in[1];
    const float* W_hh = (const float*)d_in[2];
    const float* b_ih = (const float*)d_in[3];
    const float* b_hh = (const float*)d_in[4];
    const float* W_g  = (const float*)d_in[5];
    const float* b_g  = (const float*)d_in[6];
    float* out = (float*)d_out;

    char* w = (char*)d_ws;
    float* params  = (float*)w;  w += 4096;
    float* Hx      = (float*)w;  w += NB * HID * 4;            // 524288
    float* Cx      = (float*)w;  w += NB * HID * 4;            // 524288
    u16* xcat_hi   = (u16*)w;    w += (size_t)NB * KTOT * 2;   // 2359296
    u16* xcat_lo   = (u16*)w;    w += (size_t)NB * KTOT * 2;   // 2359296
    u16* wc_hi     = (u16*)w;    w += (size_t)2048 * KTOT * 2; // 18874368
    u16* wc_lo     = (u16*)w;    w += (size_t)2048 * KTOT * 2; // 18874368
    float* part    = (float*)w;  w += (size_t)SPLITK * NB * 2048 * 4; // 16777216

    (void)hipFuncSetAttribute((const void*)k_glimpse,
                              hipFuncAttributeMaxDynamicSharedMemorySize, GLDS_BYTES);

    // zero the recurrent state and xcat (Hx columns must be 0 for step 0)
    hipMemsetAsync(Hx, 0, (size_t)2 * NB * HID * sizeof(float), stream);
    hipMemsetAsync(xcat_hi, 0, (size_t)2 * NB * KTOT * 2, stream);

    k_wsplit<<<2304, 256, 0, stream>>>(W_ih, W_hh, wc_hi, wc_lo);

    for (int step = 0; step < NSTEP; ++step) {
        k_params<<<NB, 64, 0, stream>>>(Hx, W_g, b_g, params);
        k_glimpse<<<NB, 256, GLDS_BYTES, stream>>>(params, imgs, step & 1, xcat_hi, xcat_lo);
        k_gates<<<256, 256, 0, stream>>>(xcat_hi, xcat_lo, wc_hi, wc_lo, part);
        k_lstm<<<NB * HID / 256, 256, 0, stream>>>(part, b_ih, b_hh, Cx, Hx, out, xcat_hi, xcat_lo);
    }
}

// Round 3
// 1020.151 us; speedup vs baseline: 3.5155x; 1.5045x over previous
//
#include <hip/hip_runtime.h>
#include <math.h>

#define NB 256
#define IMG 256
#define GSZ 64
#define HID 512
#define NSTEP 16
#define KTOT 4608            // 4096 (x) + 512 (Hx)
#define SPLITK 8
#define KCHUNK 576           // KTOT / SPLITK
#define KSTEPS 18            // KCHUNK / 32

#define GP 264               // Fh/Fw/t1T LDS pitch (bf16 elems); 528 B rows (16B-aligned, 2-way banks)
#define SP 40                // img-stage LDS pitch (bf16 elems); 80 B rows (k_gates-proven)
#define GLDS_BYTES (4*64*GP*2 + 512)   // 135,680 B

typedef unsigned short u16;
typedef __attribute__((ext_vector_type(8))) short s16x8;   // 8 bf16
typedef __attribute__((ext_vector_type(4))) float f32x4;

__device__ inline u16 f2bf(float f) {           // round-to-nearest-even bf16
    unsigned u = __float_as_uint(f);
    unsigned r = u + 0x7fffu + ((u >> 16) & 1u);
    return (u16)(r >> 16);
}
__device__ inline float bf2f(u16 h) { return __uint_as_float((unsigned)h << 16); }

// ---------------- weight split (once per launch): Wc = [W_ih | W_hh] -> hi/lo bf16 ----------------
__global__ __launch_bounds__(256) void k_wsplit(const float* __restrict__ W_ih,
                                                const float* __restrict__ W_hh,
                                                u16* __restrict__ wc_hi,
                                                u16* __restrict__ wc_lo) {
    const int nchunk = 2048 * KTOT / 4;
    const int stride = gridDim.x * blockDim.x;
    for (int c = blockIdx.x * blockDim.x + threadIdx.x; c < nchunk; c += stride) {
        const int j = c / (KTOT / 4);
        const int k = (c - j * (KTOT / 4)) * 4;
        float4 v;
        if (k < 4096) v = *(const float4*)&W_ih[(size_t)j * 4096 + k];
        else          v = *(const float4*)&W_hh[(size_t)j * 512 + (k - 4096)];
        float f[4] = {v.x, v.y, v.z, v.w};
        u16 hi[4], lo[4];
        #pragma unroll
        for (int i = 0; i < 4; ++i) {
            hi[i] = f2bf(f[i]);
            lo[i] = f2bf(f[i] - bf2f(hi[i]));
        }
        const size_t o = (size_t)j * KTOT + k;
        *(ushort4*)&wc_hi[o] = make_ushort4(hi[0], hi[1], hi[2], hi[3]);
        *(ushort4*)&wc_lo[o] = make_ushort4(lo[0], lo[1], lo[2], lo[3]);
    }
}

// ---------------- params: gp = tanh(Hx @ W_g^T + b_g) -> filter params ----------------
__global__ __launch_bounds__(64) void k_params(const float* __restrict__ Hx,
                                               const float* __restrict__ W_g,
                                               const float* __restrict__ b_g,
                                               float* __restrict__ params) {
    const int b = blockIdx.x;
    const int l = threadIdx.x;
    float s0 = 0.f, s1 = 0.f, s2 = 0.f;
    const float* h = Hx + (size_t)b * HID;
    for (int k = l; k < HID; k += 64) {
        float hv = h[k];
        s0 += hv * W_g[k];
        s1 += hv * W_g[HID + k];
        s2 += hv * W_g[2 * HID + k];
    }
    for (int off = 32; off; off >>= 1) {
        s0 += __shfl_xor(s0, off, 64);
        s1 += __shfl_xor(s1, off, 64);
        s2 += __shfl_xor(s2, off, 64);
    }
    if (l == 0) {
        float g0 = tanhf(s0 + b_g[0]);
        float g1 = tanhf(s1 + b_g[1]);
        float g2 = tanhf(s2 + b_g[2]);
        float ad = fabsf(g2);
        params[b * 4 + 0] = 127.5f * (g0 + 1.0f);        // center_h
        params[b * 4 + 1] = 127.5f * (g1 + 1.0f);        // center_w
        params[b * 4 + 2] = 4.0f * (1.0f - ad);          // delta
        params[b * 4 + 3] = expf(1.0f - 2.0f * ad);      // gamma
    }
}

// ---------------- glimpse via bf16x3 MFMA: x = Fhn @ (img @ Fwn^T) ----------------
__global__ __launch_bounds__(256, 1) void k_glimpse(const float* __restrict__ params,
                                                    const float* __restrict__ imgs,
                                                    int sel,
                                                    u16* __restrict__ xh,
                                                    u16* __restrict__ xl) {
    extern __shared__ u16 sm[];
    u16* FwH  = sm;                    // [64][GP] Fw hi (later t1T hi)
    u16* FwL  = sm + 64 * GP;          // [64][GP] Fw lo (later t1T lo)
    u16* R2   = sm + 2 * 64 * GP;      // region 2
    u16* AstH = R2;                    // [256][SP] img-stage hi (phase 1)
    u16* AstL = R2 + 256 * SP;         // [256][SP] img-stage lo
    u16* FhH  = R2;                    // [64][GP] Fh hi (phase 2, overwrites stage)
    u16* FhL  = R2 + 64 * GP;          // [64][GP] Fh lo
    float* invW = (float*)(sm + 4 * 64 * GP);
    float* invA = invW + 64;

    const int b = blockIdx.x, t = threadIdx.x;
    const int lane = t & 63, wv = t >> 6;
    const int fr = lane & 15, kg = lane >> 4;
    const float ch = params[b * 4 + 0];
    const float cw = params[b * 4 + 1];
    const float dl = params[b * 4 + 2];
    const float gm = params[b * 4 + 3];
    const float ig = 1.0f / gm;
    const float coef = 1.0f / (3.14159265358979323846f * gm);

    // ---- fill Fw (unnormalized, hi/lo) + row sums -> invW ----
    {
        const int r  = t >> 2;              // gw row
        const int w0 = (t & 3) * 64;        // w chunk
        const float rc = cw + dl * ((float)r - 31.5f);
        float s = 0.f;
        for (int i = 0; i < 64; i += 4) {
            u16 hh[4], ll[4];
            #pragma unroll
            for (int j = 0; j < 4; ++j) {
                float u = ((float)(w0 + i + j) - rc) * ig;
                float val = coef / (1.0f + u * u);
                s += val;
                hh[j] = f2bf(val);
                ll[j] = f2bf(val - bf2f(hh[j]));
            }
            *(ushort4*)&FwH[r * GP + w0 + i] = make_ushort4(hh[0], hh[1], hh[2], hh[3]);
            *(ushort4*)&FwL[r * GP + w0 + i] = make_ushort4(ll[0], ll[1], ll[2], ll[3]);
        }
        s += __shfl_xor(s, 1, 64);
        s += __shfl_xor(s, 2, 64);
        if ((t & 3) == 0) invW[r] = 1.0f / (s + 1e-4f);
    }
    __syncthreads();

    // ---- phase 1: t1[h][gw] = sum_w img[h][w] * Fw[gw][w]   (M=256, N=64, K=256) ----
    const float* imgp = imgs + (size_t)(b * 2 + sel) * (IMG * IMG);
    int rowA[8], coA[8];
    float4 pf[8];
    #pragma unroll
    for (int q = 0; q < 8; ++q) {
        const int c = q * 256 + t;
        rowA[q] = c >> 3;
        coA[q]  = (c & 7) * 4;
        pf[q] = *(const float4*)&imgp[rowA[q] * IMG + coA[q]];
    }
    f32x4 acc[4][4];
    #pragma unroll
    for (int mi = 0; mi < 4; ++mi)
        #pragma unroll
        for (int ni = 0; ni < 4; ++ni) acc[mi][ni] = (f32x4)(0.f);

    for (int ks = 0; ks < 8; ++ks) {
        __syncthreads();
        #pragma unroll
        for (int q = 0; q < 8; ++q) {
            float f[4] = {pf[q].x, pf[q].y, pf[q].z, pf[q].w};
            u16 hh[4], ll[4];
            #pragma unroll
            for (int j = 0; j < 4; ++j) {
                hh[j] = f2bf(f[j]);
                ll[j] = f2bf(f[j] - bf2f(hh[j]));
            }
            *(ushort4*)&AstH[rowA[q] * SP + coA[q]] = make_ushort4(hh[0], hh[1], hh[2], hh[3]);
            *(ushort4*)&AstL[rowA[q] * SP + coA[q]] = make_ushort4(ll[0], ll[1], ll[2], ll[3]);
        }
        __syncthreads();
        if (ks < 7) {
            #pragma unroll
            for (int q = 0; q < 8; ++q)
                pf[q] = *(const float4*)&imgp[rowA[q] * IMG + (ks + 1) * 32 + coA[q]];
        }
        s16x8 ah[4], al[4], bh[4], bl[4];
        #pragma unroll
        for (int mi = 0; mi < 4; ++mi) {
            const int r = wv * 64 + mi * 16 + fr;
            ah[mi] = *(const s16x8*)&AstH[r * SP + kg * 8];
            al[mi] = *(const s16x8*)&AstL[r * SP + kg * 8];
        }
        #pragma unroll
        for (int ni = 0; ni < 4; ++ni) {
            const int r = ni * 16 + fr;
            bh[ni] = *(const s16x8*)&FwH[r * GP + ks * 32 + kg * 8];
            bl[ni] = *(const s16x8*)&FwL[r * GP + ks * 32 + kg * 8];
        }
        #pragma unroll
        for (int mi = 0; mi < 4; ++mi)
            #pragma unroll
            for (int ni = 0; ni < 4; ++ni) {
                acc[mi][ni] = __builtin_amdgcn_mfma_f32_16x16x32_bf16(ah[mi], bh[ni], acc[mi][ni], 0, 0, 0);
                acc[mi][ni] = __builtin_amdgcn_mfma_f32_16x16x32_bf16(ah[mi], bl[ni], acc[mi][ni], 0, 0, 0);
                acc[mi][ni] = __builtin_amdgcn_mfma_f32_16x16x32_bf16(al[mi], bh[ni], acc[mi][ni], 0, 0, 0);
            }
    }
    __syncthreads();   // all Fw / img-stage reads done

    // ---- scale t1 cols by invW, split hi/lo, write t1T[gw][h] over Fw region ----
    #pragma unroll
    for (int ni = 0; ni < 4; ++ni) {
        const int col = ni * 16 + fr;          // gw
        const float s = invW[col];
        #pragma unroll
        for (int mi = 0; mi < 4; ++mi) {
            const int hbase = wv * 64 + mi * 16 + kg * 4;   // h
            u16 hh[4], ll[4];
            #pragma unroll
            for (int r = 0; r < 4; ++r) {
                float v = acc[mi][ni][r] * s;
                hh[r] = f2bf(v);
                ll[r] = f2bf(v - bf2f(hh[r]));
            }
            *(ushort4*)&FwH[col * GP + hbase] = make_ushort4(hh[0], hh[1], hh[2], hh[3]);
            *(ushort4*)&FwL[col * GP + hbase] = make_ushort4(ll[0], ll[1], ll[2], ll[3]);
        }
    }

    // ---- fill Fh (unnormalized, hi/lo) into region 2 + row sums -> invA ----
    {
        const int r  = t >> 2;              // gh row
        const int h0 = (t & 3) * 64;        // h chunk
        const float rc = ch + dl * ((float)r - 31.5f);
        float s = 0.f;
        for (int i = 0; i < 64; i += 4) {
            u16 hh[4], ll[4];
            #pragma unroll
            for (int j = 0; j < 4; ++j) {
                float u = ((float)(h0 + i + j) - rc) * ig;
                float val = coef / (1.0f + u * u);
                s += val;
                hh[j] = f2bf(val);
                ll[j] = f2bf(val - bf2f(hh[j]));
            }
            *(ushort4*)&FhH[r * GP + h0 + i] = make_ushort4(hh[0], hh[1], hh[2], hh[3]);
            *(ushort4*)&FhL[r * GP + h0 + i] = make_ushort4(ll[0], ll[1], ll[2], ll[3]);
        }
        s += __shfl_xor(s, 1, 64);
        s += __shfl_xor(s, 2, 64);
        if ((t & 3) == 0) invA[r] = 1.0f / (s + 1e-4f);
    }
    __syncthreads();

    // ---- phase 2: x[gh][gw] = invA[gh] * sum_h Fh[gh][h] * t1T[gw][h]  (M=64,N=64,K=256) ----
    f32x4 acc2[4];
    #pragma unroll
    for (int ni = 0; ni < 4; ++ni) acc2[ni] = (f32x4)(0.f);

    #pragma unroll
    for (int ks = 0; ks < 8; ++ks) {
        const int ra = wv * 16 + fr;
        s16x8 a2h = *(const s16x8*)&FhH[ra * GP + ks * 32 + kg * 8];
        s16x8 a2l = *(const s16x8*)&FhL[ra * GP + ks * 32 + kg * 8];
        #pragma unroll
        for (int ni = 0; ni < 4; ++ni) {
            const int rb = ni * 16 + fr;
            s16x8 b2h = *(const s16x8*)&FwH[rb * GP + ks * 32 + kg * 8];
            s16x8 b2l = *(const s16x8*)&FwL[rb * GP + ks * 32 + kg * 8];
            acc2[ni] = __builtin_amdgcn_mfma_f32_16x16x32_bf16(a2h, b2h, acc2[ni], 0, 0, 0);
            acc2[ni] = __builtin_amdgcn_mfma_f32_16x16x32_bf16(a2h, b2l, acc2[ni], 0, 0, 0);
            acc2[ni] = __builtin_amdgcn_mfma_f32_16x16x32_bf16(a2l, b2h, acc2[ni], 0, 0, 0);
        }
    }
    const int rbase = wv * 16 + kg * 4;
    float ia[4];
    #pragma unroll
    for (int r = 0; r < 4; ++r) ia[r] = invA[rbase + r];
    u16* xho = xh + (size_t)b * KTOT;
    u16* xlo = xl + (size_t)b * KTOT;
    #pragma unroll
    for (int ni = 0; ni < 4; ++ni) {
        const int col = ni * 16 + fr;
        #pragma unroll
        for (int r = 0; r < 4; ++r) {
            float v = acc2[ni][r] * ia[r];
            u16 hv = f2bf(v);
            const int o = (rbase + r) * GSZ + col;
            xho[o] = hv;
            xlo[o] = f2bf(v - bf2f(hv));
        }
    }
}

// ---------------- gates GEMM via bf16x3 MFMA, split-K partials ----------------
__global__ __launch_bounds__(256) void k_gates(const u16* __restrict__ xcat_hi,
                                               const u16* __restrict__ xcat_lo,
                                               const u16* __restrict__ wc_hi,
                                               const u16* __restrict__ wc_lo,
                                               float* __restrict__ part) {
    __shared__ u16 smem[4][128][40];

    const int bid = blockIdx.x;
    const int mb = bid & 1;
    const int nb = (bid >> 1) & 15;
    const int kc = bid >> 5;
    const int m0 = mb * 128, n0 = nb * 128, k0 = kc * KCHUNK;
    const int t = threadIdx.x;
    const int lane = t & 63, wid = t >> 6;
    const int wm = wid >> 1, wn = wid & 1;
    const int fr = lane & 15, kg = lane >> 4;

    const u16* srcs[8];
    u16* dsts[8];
    #pragma unroll
    for (int q = 0; q < 8; ++q) {
        const int idx = ((q * 256 + t) & 511);
        const int row = idx >> 2;
        const int ko = (idx & 3) * 8;
        const int mat = q >> 1;
        const u16* gbase;
        if (mat == 0)      gbase = xcat_hi + (size_t)(m0 + row) * KTOT;
        else if (mat == 1) gbase = xcat_lo + (size_t)(m0 + row) * KTOT;
        else if (mat == 2) gbase = wc_hi + (size_t)(n0 + row) * KTOT;
        else               gbase = wc_lo + (size_t)(n0 + row) * KTOT;
        srcs[q] = gbase + k0 + ko;
        dsts[q] = &smem[mat][row][ko];
    }

    f32x4 acc[4][4];
    #pragma unroll
    for (int mi = 0; mi < 4; ++mi)
        #pragma unroll
        for (int ni = 0; ni < 4; ++ni) acc[mi][ni] = (f32x4)(0.f);

    s16x8 ld[8];
    #pragma unroll
    for (int q = 0; q < 8; ++q) ld[q] = *(const s16x8*)(srcs[q]);

    for (int ks = 0; ks < KSTEPS; ++ks) {
        __syncthreads();
        #pragma unroll
        for (int q = 0; q < 8; ++q) {
            *(s16x8*)(dsts[q]) = ld[q];
            srcs[q] += 32;
        }
        __syncthreads();
        if (ks + 1 < KSTEPS) {
            #pragma unroll
            for (int q = 0; q < 8; ++q) ld[q] = *(const s16x8*)(srcs[q]);
        }
        s16x8 ah[4], al[4], bh[4], bl[4];
        #pragma unroll
        for (int mi = 0; mi < 4; ++mi) {
            const int r = wm * 64 + mi * 16 + fr;
            ah[mi] = *(const s16x8*)&smem[0][r][kg * 8];
            al[mi] = *(const s16x8*)&smem[1][r][kg * 8];
        }
        #pragma unroll
        for (int ni = 0; ni < 4; ++ni) {
            const int r = wn * 64 + ni * 16 + fr;
            bh[ni] = *(const s16x8*)&smem[2][r][kg * 8];
            bl[ni] = *(const s16x8*)&smem[3][r][kg * 8];
        }
        #pragma unroll
        for (int mi = 0; mi < 4; ++mi)
            #pragma unroll
            for (int ni = 0; ni < 4; ++ni) {
                acc[mi][ni] = __builtin_amdgcn_mfma_f32_16x16x32_bf16(ah[mi], bh[ni], acc[mi][ni], 0, 0, 0);
                acc[mi][ni] = __builtin_amdgcn_mfma_f32_16x16x32_bf16(ah[mi], bl[ni], acc[mi][ni], 0, 0, 0);
                acc[mi][ni] = __builtin_amdgcn_mfma_f32_16x16x32_bf16(al[mi], bh[ni], acc[mi][ni], 0, 0, 0);
            }
    }

    float* pp = part + ((size_t)kc << 19);
    #pragma unroll
    for (int mi = 0; mi < 4; ++mi) {
        const int mbase = m0 + wm * 64 + mi * 16 + (lane >> 4) * 4;
        #pragma unroll
        for (int ni = 0; ni < 4; ++ni) {
            const int col = n0 + wn * 64 + ni * 16 + (lane & 15);
            #pragma unroll
            for (int r = 0; r < 4; ++r)
                pp[(size_t)(mbase + r) * 2048 + col] = acc[mi][ni][r];
        }
    }
}

// ---------------- pointwise LSTM update (+ split-K reduce, biases) ----------------
__global__ __launch_bounds__(256) void k_lstm(const float* __restrict__ part,
                                              const float* __restrict__ b_ih,
                                              const float* __restrict__ b_hh,
                                              float* __restrict__ Cx,
                                              float* __restrict__ Hx,
                                              float* __restrict__ out,
                                              u16* __restrict__ xcat_hi,
                                              u16* __restrict__ xcat_lo) {
    const int id = blockIdx.x * 256 + threadIdx.x;
    const int b = id >> 9, u = id & (HID - 1);
    float gi = b_ih[u] + b_hh[u];
    float gf = b_ih[HID + u] + b_hh[HID + u];
    float gg = b_ih[2 * HID + u] + b_hh[2 * HID + u];
    float go = b_ih[3 * HID + u] + b_hh[3 * HID + u];
    const float* pb = part + (size_t)b * 2048;
    #pragma unroll
    for (int kc = 0; kc < SPLITK; ++kc) {
        const float* p = pb + (size_t)kc * (256 * 2048);
        gi += p[u];
        gf += p[HID + u];
        gg += p[2 * HID + u];
        go += p[3 * HID + u];
    }
    float si = 1.0f / (1.0f + expf(-gi));
    float sf = 1.0f / (1.0f + expf(-gf));
    float so = 1.0f / (1.0f + expf(-go));
    float c = sf * Cx[id] + si * tanhf(gg);
    float h = so * tanhf(c);
    Cx[id] = c;
    Hx[id] = h;
    out[id] = h;
    u16 hh = f2bf(h);
    xcat_hi[(size_t)b * KTOT + 4096 + u] = hh;
    xcat_lo[(size_t)b * KTOT + 4096 + u] = f2bf(h - bf2f(hh));
}

extern "C" void kernel_launch(void* const* d_in, const int* in_sizes, int n_in,
                              void* d_out, int out_size, void* d_ws, size_t ws_size,
                              hipStream_t stream) {
    const float* imgs = (const float*)d_in[0];
    const float* W_ih = (const float*)d_in[1];
    const float* W_hh = (const float*)d_in[2];
    const float* b_ih = (const float*)d_in[3];
    const float* b_hh = (const float*)d_in[4];
    const float* W_g  = (const float*)d_in[5];
    const float* b_g  = (const float*)d_in[6];
    float* out = (float*)d_out;

    char* w = (char*)d_ws;
    float* params  = (float*)w;  w += 4096;
    float* Hx      = (float*)w;  w += NB * HID * 4;
    float* Cx      = (float*)w;  w += NB * HID * 4;
    u16* xcat_hi   = (u16*)w;    w += (size_t)NB * KTOT * 2;
    u16* xcat_lo   = (u16*)w;    w += (size_t)NB * KTOT * 2;
    u16* wc_hi     = (u16*)w;    w += (size_t)2048 * KTOT * 2;
    u16* wc_lo     = (u16*)w;    w += (size_t)2048 * KTOT * 2;
    float* part    = (float*)w;  w += (size_t)SPLITK * NB * 2048 * 4;

    (void)hipFuncSetAttribute((const void*)k_glimpse,
                              hipFuncAttributeMaxDynamicSharedMemorySize, GLDS_BYTES);

    hipMemsetAsync(Hx, 0, (size_t)2 * NB * HID * sizeof(float), stream);
    hipMemsetAsync(xcat_hi, 0, (size_t)2 * NB * KTOT * 2, stream);

    k_wsplit<<<2304, 256, 0, stream>>>(W_ih, W_hh, wc_hi, wc_lo);

    for (int step = 0; step < NSTEP; ++step) {
        k_params<<<NB, 64, 0, stream>>>(Hx, W_g, b_g, params);
        k_glimpse<<<NB, 256, GLDS_BYTES, stream>>>(params, imgs, step & 1, xcat_hi, xcat_lo);
        k_gates<<<256, 256, 0, stream>>>(xcat_hi, xcat_lo, wc_hi, wc_lo, part);
        k_lstm<<<NB * HID / 256, 256, 0, stream>>>(part, b_ih, b_hh, Cx, Hx, out, xcat_hi, xcat_lo);
    }
}